// Round 1
// baseline (218.281 us; speedup 1.0000x reference)
//
#include <hip/hip_runtime.h>
#include <math.h>

#define T_DIM 512
#define TP 8
#define H 16
#define N_K 2
#define N_TRNBR 128
#define K_VOCAB 128
#define D_DIM 256
#define C_CNC 65          // 2*H*N_K + 1
#define NPOS 256          // N_TRNBR + K_VOCAB
#define BLOCK 576

// integer "cosine similarity": sign * (1 - (floor(log2(|a|^|b| + 1)) + 1)/H)
__device__ __forceinline__ float cos_sim(int c1, int c2) {
    float sg = ((c1 >= 0) == (c2 >= 0)) ? 1.0f : -1.0f;
    int a1 = c1 < 0 ? -c1 : c1;
    int a2 = c2 < 0 ? -c2 : c2;
    int x = (a1 ^ a2) + 1;            // x >= 1
    int expo = 32 - __clz(x);         // floor(log2(x)) + 1
    return sg * (1.0f - (float)expo * 0.0625f);
}

__global__ __launch_bounds__(BLOCK) void critigraph_kernel(
    const int* __restrict__ sta_loc,    // (T, TP)
    const int* __restrict__ nei_loc,    // (T, 128, TP)
    const int* __restrict__ voc_loc,    // (T, 128, TP)
    const float* __restrict__ sta_emb,  // (T, 256)
    const float* __restrict__ nei_emb,  // (T, 128, 256)
    const float* __restrict__ voc_emb,  // (T, 128, 256)
    const int* __restrict__ rand_masks, // (T, 16, 2, TP)
    float* __restrict__ out)            // [4096 locs][512 cos][512 cro][512 tot]
{
    const int t = blockIdx.x;
    const int tid = threadIdx.x;

    __shared__ int   s_sta[TP];
    __shared__ int   s_rand[H * N_K * TP];        // 256 ints
    __shared__ int   s_pos[NPOS * TP];            // 8 KB
    __shared__ float s_csp[NPOS * TP];            // 8 KB  cos(sta, pos)
    __shared__ float s_css[NPOS];                 // sum over p
    __shared__ float s_eu[128];                   // eu_cos_val
    __shared__ float s_nrm[128];                  // eu_cro_nrm
    __shared__ float s_dot[128], s_nn[128], s_vv[128];
    __shared__ float s_ss;
    __shared__ float s_lcos[C_CNC * TP], s_lcro[C_CNC * TP], s_ltot[C_CNC * TP];
    __shared__ int   s_cnc[C_CNC * TP];
    __shared__ float s_sel[3 * TP];

    if (tid < TP) s_sta[tid] = sta_loc[t * TP + tid];
    if (tid < H * N_K * TP) s_rand[tid] = rand_masks[t * H * N_K * TP + tid];

    // ---- phase 1: embedding dots & norms (4 threads per n) ----
    if (tid < 512) {
        const int g = tid >> 2, sub = tid & 3;
        const float4* sp = reinterpret_cast<const float4*>(sta_emb + (size_t)t * D_DIM);
        const float4* np_ = reinterpret_cast<const float4*>(nei_emb + ((size_t)t * 128 + g) * D_DIM);
        const float4* vp = reinterpret_cast<const float4*>(voc_emb + ((size_t)t * 128 + g) * D_DIM);
        float sd = 0.f, nn = 0.f, vv = 0.f, ss = 0.f;
        #pragma unroll
        for (int i = 0; i < 16; ++i) {
            const int i4 = sub + 4 * i;           // covers 0..63
            float4 a = sp[i4];
            float4 b = np_[i4];
            float4 c = vp[i4];
            sd += a.x * b.x + a.y * b.y + a.z * b.z + a.w * b.w;
            nn += b.x * b.x + b.y * b.y + b.z * b.z + b.w * b.w;
            vv += c.x * c.x + c.y * c.y + c.z * c.z + c.w * c.w;
            ss += a.x * a.x + a.y * a.y + a.z * a.z + a.w * a.w;
        }
        sd += __shfl_xor(sd, 1); sd += __shfl_xor(sd, 2);
        nn += __shfl_xor(nn, 1); nn += __shfl_xor(nn, 2);
        vv += __shfl_xor(vv, 1); vv += __shfl_xor(vv, 2);
        ss += __shfl_xor(ss, 1); ss += __shfl_xor(ss, 2);
        if (sub == 0) {
            s_dot[g] = sd; s_nn[g] = nn; s_vv[g] = vv;
            if (g == 0) s_ss = ss;
        }
    }
    __syncthreads();

    if (tid < 128) {
        const float ns = sqrtf(s_ss);
        const float cs = fmaxf(ns, 1e-12f);
        const float cn = fmaxf(sqrtf(s_nn[tid]), 1e-12f);
        s_eu[tid] = s_dot[tid] / (cn * cs);
        s_nrm[tid] = ns * sqrtf(s_vv[tid]);
    }

    // ---- phase 2: stage pos_loc + cos(sta, pos) ----
    for (int item = tid; item < NPOS * TP; item += BLOCK) {
        const int j = item >> 3, p = item & 7;
        const int pl = (j < 128) ? nei_loc[((size_t)t * 128 + j) * TP + p]
                                 : voc_loc[((size_t)t * 128 + (j - 128)) * TP + p];
        s_pos[j * TP + p] = pl;
        s_csp[j * TP + p] = cos_sim(s_sta[p], pl);
    }
    __syncthreads();

    if (tid < NPOS) {
        float s = 0.f;
        #pragma unroll
        for (int p = 0; p < TP; ++p) s += s_csp[tid * TP + p];
        s_css[tid] = s;
    }
    __syncthreads();

    // ---- phase 3: one thread per (c, p) ----
    if (tid < C_CNC * TP) {
        const int c = tid >> 3, p = tid & 7;
        const int sta = s_sta[p];
        int v;
        if (c == 32) {
            v = sta;
        } else {
            const int cc = (c < 32) ? c : (c - 33);
            const int h = cc >> 1, k = cc & 1;
            const int r = (sta ^ (1 << h)) ^ (s_rand[(h * N_K + k) * TP + p] & ((1 << h) - 1));
            v = (c < 32) ? r : -r;
        }

        // loss_cos over nei (j = 0..127)
        float lc = 0.f;
        for (int j = 0; j < 128; ++j) {
            const float ct = (s_css[j] - s_csp[j * TP + p] + cos_sim(v, s_pos[j * TP + p])) * 0.125f;
            const float e = s_eu[j];
            const float d = ct - e;
            lc += d * d * fabsf(e);
        }
        lc *= (1.0f / 128.0f);   // lth = 128 + 1e-12 rounds to 128.0f

        // loss_cro over vocab (k = 0..127), online logsumexp
        const float CORR = logf(50257.0f / 128.0f);
        float m = -INFINITY, ssum = 0.f, z0 = 0.f;
        for (int k = 0; k < 128; ++k) {
            const int j = 128 + k;
            const float ct = (s_css[j] - s_csp[j * TP + p] + cos_sim(v, s_pos[j * TP + p])) * 0.125f;
            const float z = ct * s_nrm[k] + ((k == 0) ? 0.0f : CORR);
            if (k == 0) z0 = z;
            const float nm = fmaxf(m, z);
            ssum = ssum * expf(m - nm) + expf(z - nm);
            m = nm;
        }
        const float lcro = m + logf(ssum) - z0;

        s_lcos[c * TP + p] = lc;
        s_lcro[c * TP + p] = lcro;
        s_ltot[c * TP + p] = lc + 0.1f * lcro;
        s_cnc[c * TP + p] = v;
    }
    __syncthreads();

    // ---- phase 4: argmin over c (first-min), gather, write ----
    if (tid < TP) {
        const int p = tid;
        float best = s_ltot[p];
        int bi = 0;
        for (int c = 1; c < C_CNC; ++c) {
            const float vv = s_ltot[c * TP + p];
            if (vv < best) { best = vv; bi = c; }
        }
        out[t * TP + p] = (float)s_cnc[bi * TP + p];
        s_sel[p] = s_lcos[bi * TP + p];
        s_sel[TP + p] = s_lcro[bi * TP + p];
        s_sel[2 * TP + p] = s_ltot[bi * TP + p];
    }
    __syncthreads();

    if (tid == 0) {
        float a = 0.f, b = 0.f, c = 0.f;
        #pragma unroll
        for (int p = 0; p < TP; ++p) {
            a += s_sel[p]; b += s_sel[TP + p]; c += s_sel[2 * TP + p];
        }
        out[T_DIM * TP + t] = a * (1.0f / TP);
        out[T_DIM * TP + T_DIM + t] = b * (1.0f / TP);
        out[T_DIM * TP + 2 * T_DIM + t] = c * (1.0f / TP);
    }
}

extern "C" void kernel_launch(void* const* d_in, const int* in_sizes, int n_in,
                              void* d_out, int out_size, void* d_ws, size_t ws_size,
                              hipStream_t stream) {
    const int* sta_loc = (const int*)d_in[0];
    const int* nei_loc = (const int*)d_in[1];
    const int* voc_loc = (const int*)d_in[2];
    const float* sta_emb = (const float*)d_in[3];
    const float* nei_emb = (const float*)d_in[4];
    const float* voc_emb = (const float*)d_in[5];
    const int* rand_masks = (const int*)d_in[6];
    // d_in[7] = mask: all-ones by construction; lth = 128
    float* out = (float*)d_out;

    critigraph_kernel<<<T_DIM, BLOCK, 0, stream>>>(
        sta_loc, nei_loc, voc_loc, sta_emb, nei_emb, voc_emb, rand_masks, out);
}

// Round 2
// 218.169 us; speedup vs baseline: 1.0005x; 1.0005x over previous
//
#include <hip/hip_runtime.h>
#include <math.h>

#define T_DIM 512
#define TP 8
#define NC 65            // 2*16*2 + 1 candidates
#define NJ 128           // nei count == vocab count
#define LOG2E 1.4426950408889634f
#define LN2   0.6931471805599453f

// cos_sim core: va=|v|, vs = sign bit of v, qmix = |q| | signbit(q)
// returns sign(v)*sign(q) * (1 - (floor(log2(|v|^|q| + 1)) + 1)/16)
//       = +- (clz(x+1)/16 - 1)
__device__ __forceinline__ float csim(int va, int vs, int qmix) {
    const int sgn = (vs ^ qmix) & 0x80000000;
    const int x = va ^ (qmix & 0x7fffffff);
    const float u0 = fmaf((float)__clz(x + 1), 0.0625f, -1.0f);
    return __int_as_float(__float_as_int(u0) ^ sgn);
}

__device__ __forceinline__ int make_v(int c, int sta, int rnd_cc_h /*rand value*/, int h) {
    // caller resolves cc/h and loads rand; here just combine
    const int r = (sta ^ (1 << h)) ^ (rnd_cc_h & ((1 << h) - 1));
    return r;
}

// ---------------- main kernel: grid (512, 2), block 512 ----------------
// side 0: loss_cos (nei). side 1: loss_cro (voc). writes ws arrays.
__global__ __launch_bounds__(512, 8) void cg_main(
    const int* __restrict__ sta_loc,    // (T, 8)
    const int* __restrict__ nei_loc,    // (T, 128, 8)
    const int* __restrict__ voc_loc,    // (T, 128, 8)
    const float* __restrict__ sta_emb,  // (T, 256)
    const float* __restrict__ nei_emb,  // (T, 128, 256)
    const float* __restrict__ voc_emb,  // (T, 128, 256)
    const int* __restrict__ rand_masks, // (T, 32, 8)
    float* __restrict__ wcos,           // (T, 65, 8)
    float* __restrict__ wcro)           // (T, 65, 8)
{
    const int t = blockIdx.x;
    const int side = blockIdx.y;
    const int tid = threadIdx.x;

    __shared__ int2  s_pc[NJ * TP];   // 8 KB: {qmix, csp -> base/C}
    __shared__ float s_w[NJ];         // eu (side0) or A_k (side1)
    __shared__ float s_css[NJ];
    __shared__ float s_dot[NJ], s_nn[NJ];
    __shared__ float s_ss;
    __shared__ int   s_sta[TP];
    __shared__ int   s_rand[256];

    if (tid < TP) s_sta[tid] = sta_loc[t * TP + tid];
    if (tid < 256) s_rand[tid] = rand_masks[t * 256 + tid];

    // --- embedding partial sums: 4 threads per row ---
    {
        const float* emb = (side == 0) ? nei_emb : voc_emb;
        const int g = tid >> 2, sub = tid & 3;
        const float4* ep = (const float4*)(emb + ((size_t)t * NJ + g) * 256);
        const float4* sp = (const float4*)(sta_emb + (size_t)t * 256);
        float dd = 0.f, nn = 0.f, ss = 0.f;
        #pragma unroll
        for (int i = 0; i < 16; ++i) {
            const int i4 = sub + 4 * i;
            const float4 a = sp[i4];
            const float4 b = ep[i4];
            dd += a.x * b.x + a.y * b.y + a.z * b.z + a.w * b.w;
            nn += b.x * b.x + b.y * b.y + b.z * b.z + b.w * b.w;
            if (g == 0) ss += a.x * a.x + a.y * a.y + a.z * a.z + a.w * a.w;
        }
        dd += __shfl_xor(dd, 1); dd += __shfl_xor(dd, 2);
        nn += __shfl_xor(nn, 1); nn += __shfl_xor(nn, 2);
        if (g == 0) { ss += __shfl_xor(ss, 1); ss += __shfl_xor(ss, 2); }
        if (sub == 0) { s_dot[g] = dd; s_nn[g] = nn; if (g == 0) s_ss = ss; }
    }
    __syncthreads();

    // --- int staging: qmix + csp ---
    {
        const int* loc = (side == 0) ? nei_loc : voc_loc;
        #pragma unroll
        for (int item = tid; item < NJ * TP; item += 512) {
            const int p = item & 7;
            const int pl = loc[(size_t)t * (NJ * TP) + item];
            const int qm = (pl < 0 ? -pl : pl) | (pl & 0x80000000);
            const int sta = s_sta[p];
            const float csp = csim(sta < 0 ? -sta : sta, sta & 0x80000000, qm);
            s_pc[item].x = qm;
            s_pc[item].y = __float_as_int(csp);
        }
    }
    __syncthreads();

    // --- per-j reductions: css, eu / A ---
    if (tid < NJ) {
        float cs = 0.f;
        #pragma unroll
        for (int p = 0; p < TP; ++p) cs += __int_as_float(s_pc[tid * TP + p].y);
        s_css[tid] = cs;
        const float ns = sqrtf(s_ss);
        if (side == 0) {
            s_w[tid] = s_dot[tid] / (fmaxf(sqrtf(s_nn[tid]), 1e-12f) * fmaxf(ns, 1e-12f));
        } else {
            s_w[tid] = ns * sqrtf(s_nn[tid]) * (0.125f * LOG2E);  // A_k
        }
    }
    __syncthreads();

    // --- repack .y: base (side0) or C = base*A + corr*log2e (side1) ---
    {
        const float corrl2 = logf(50257.0f / 128.0f) * LOG2E;
        #pragma unroll
        for (int item = tid; item < NJ * TP; item += 512) {
            const int j = item >> 3;
            const float csp = __int_as_float(s_pc[item].y);
            const float b = s_css[j] - csp;
            float val;
            if (side == 0) val = b;
            else val = fmaf(b, s_w[j], (j == 0) ? 0.0f : corrl2);
            s_pc[item].y = __float_as_int(val);
        }
    }
    __syncthreads();

    // --- phase 3 main: thread tid -> (c = tid>>3 in 0..63, p = tid&7) ---
    {
        const int c = tid >> 3, p = tid & 7;
        const int sta = s_sta[p];
        int v;
        if (c == 32) v = sta;
        else {
            const int cc = (c < 32) ? c : (c - 33);
            const int h = cc >> 1;
            const int r = make_v(c, sta, s_rand[cc * TP + p], h);
            v = (c < 32) ? r : -r;
        }
        const int va = v < 0 ? -v : v;
        const int vs = v & 0x80000000;

        if (side == 0) {
            float lc = 0.f;
            #pragma unroll 4
            for (int j = 0; j < NJ; ++j) {
                const int2 pc = s_pc[j * TP + p];
                const float u = csim(va, vs, pc.x);
                const float e = s_w[j];
                const float d = fmaf(__int_as_float(pc.y) + u, 0.125f, -e);
                lc = fmaf(d * d, fabsf(e), lc);
            }
            wcos[((size_t)t * NC + c) * TP + p] = lc * 0.0078125f;
        } else {
            const int2 pc0 = s_pc[p];
            const float u0 = csim(va, vs, pc0.x);
            const float z0 = fmaf(u0, s_w[0], __int_as_float(pc0.y));
            float m = z0, s = 1.0f;
            #pragma unroll 4
            for (int k = 1; k < NJ; ++k) {
                const int2 pc = s_pc[k * TP + p];
                const float u = csim(va, vs, pc.x);
                const float z = fmaf(u, s_w[k], __int_as_float(pc.y));
                const float nm = fmaxf(m, z);
                const float e = exp2f(fminf(z, m) - nm);
                const bool gt = z > m;
                s = fmaf(s, gt ? e : 1.0f, gt ? 1.0f : e);
                m = nm;
            }
            wcro[((size_t)t * NC + c) * TP + p] = (m - z0 + log2f(s)) * LN2;
        }
    }

    // --- phase 3 coop: c = 64 (= -res, h=15,k=1), wave w handles p=w ---
    {
        const int p = tid >> 6;
        const int lane = tid & 63;
        const int sta = s_sta[p];
        const int v = -((sta ^ (1 << 15)) ^ (s_rand[31 * TP + p] & 0x7fff));
        const int va = v < 0 ? -v : v;
        const int vs = v & 0x80000000;

        if (side == 0) {
            float lc = 0.f;
            #pragma unroll
            for (int jj = 0; jj < 2; ++jj) {
                const int j = 2 * lane + jj;
                const int2 pc = s_pc[j * TP + p];
                const float u = csim(va, vs, pc.x);
                const float e = s_w[j];
                const float d = fmaf(__int_as_float(pc.y) + u, 0.125f, -e);
                lc = fmaf(d * d, fabsf(e), lc);
            }
            #pragma unroll
            for (int off = 1; off < 64; off <<= 1) lc += __shfl_xor(lc, off);
            if (lane == 0) wcos[((size_t)t * NC + 64) * TP + p] = lc * 0.0078125f;
        } else {
            const int ka = 2 * lane, kb = 2 * lane + 1;
            const int2 pa = s_pc[ka * TP + p];
            const int2 pb = s_pc[kb * TP + p];
            const float za = fmaf(csim(va, vs, pa.x), s_w[ka], __int_as_float(pa.y));
            const float zb = fmaf(csim(va, vs, pb.x), s_w[kb], __int_as_float(pb.y));
            float m = fmaxf(za, zb);
            float s = exp2f(za - m) + exp2f(zb - m);
            const float z0 = za;   // k==0 lives on lane 0
            #pragma unroll
            for (int off = 1; off < 64; off <<= 1) {
                const float om = __shfl_xor(m, off);
                const float os = __shfl_xor(s, off);
                const float nm = fmaxf(m, om);
                s = fmaf(s, exp2f(m - nm), os * exp2f(om - nm));
                m = nm;
            }
            if (lane == 0) wcro[((size_t)t * NC + 64) * TP + p] = (m - z0 + log2f(s)) * LN2;
        }
    }
}

// ---------------- finalize: argmin + gather + means. grid 512 x 64 ----------------
__global__ __launch_bounds__(64) void cg_fin(
    const int* __restrict__ sta_loc, const int* __restrict__ rand_masks,
    const float* __restrict__ wcos, const float* __restrict__ wcro,
    float* __restrict__ out)
{
    const int t = blockIdx.x;
    const int tid = threadIdx.x;
    float sc = 0.f, sr = 0.f, st = 0.f;
    if (tid < TP) {
        const float* pc = wcos + (size_t)t * NC * TP + tid;
        const float* pr = wcro + (size_t)t * NC * TP + tid;
        float best = INFINITY, blc = 0.f, blr = 0.f;
        int bc = 0;
        for (int c = 0; c < NC; ++c) {
            const float lc = pc[c * TP];
            const float lr = pr[c * TP];
            const float lt = fmaf(0.1f, lr, lc);
            if (lt < best) { best = lt; bc = c; blc = lc; blr = lr; }
        }
        const int sta = sta_loc[t * TP + tid];
        int v;
        if (bc == 32) v = sta;
        else {
            const int cc = (bc < 32) ? bc : (bc - 33);
            const int h = cc >> 1;
            const int r = (sta ^ (1 << h)) ^ (rand_masks[t * 256 + cc * TP + tid] & ((1 << h) - 1));
            v = (bc < 32) ? r : -r;
        }
        out[t * TP + tid] = (float)v;
        sc = blc; sr = blr; st = best;
    }
    sc += __shfl_xor(sc, 1); sc += __shfl_xor(sc, 2); sc += __shfl_xor(sc, 4);
    sr += __shfl_xor(sr, 1); sr += __shfl_xor(sr, 2); sr += __shfl_xor(sr, 4);
    st += __shfl_xor(st, 1); st += __shfl_xor(st, 2); st += __shfl_xor(st, 4);
    if (tid == 0) {
        out[T_DIM * TP + t] = sc * 0.125f;
        out[T_DIM * TP + T_DIM + t] = sr * 0.125f;
        out[T_DIM * TP + 2 * T_DIM + t] = st * 0.125f;
    }
}

extern "C" void kernel_launch(void* const* d_in, const int* in_sizes, int n_in,
                              void* d_out, int out_size, void* d_ws, size_t ws_size,
                              hipStream_t stream) {
    const int* sta_loc = (const int*)d_in[0];
    const int* nei_loc = (const int*)d_in[1];
    const int* voc_loc = (const int*)d_in[2];
    const float* sta_emb = (const float*)d_in[3];
    const float* nei_emb = (const float*)d_in[4];
    const float* voc_emb = (const float*)d_in[5];
    const int* rand_masks = (const int*)d_in[6];
    float* out = (float*)d_out;

    float* wcos = (float*)d_ws;                       // 512*65*8 f32
    float* wcro = wcos + (size_t)T_DIM * NC * TP;     // 512*65*8 f32  (2.03 MB total)

    cg_main<<<dim3(T_DIM, 2), 512, 0, stream>>>(
        sta_loc, nei_loc, voc_loc, sta_emb, nei_emb, voc_emb, rand_masks, wcos, wcro);
    cg_fin<<<T_DIM, 64, 0, stream>>>(sta_loc, rand_masks, wcos, wcro, out);
}

// Round 4
// 210.070 us; speedup vs baseline: 1.0391x; 1.0386x over previous
//
#include <hip/hip_runtime.h>
#include <math.h>

#define T_DIM 512
#define TP 8
#define NC 65            // 2*16*2 + 1 candidates
#define NJ 128
#define BLOCK 576        // 9 waves; P5 uses 520 threads (one per (c,p))
#define LOG2E 1.4426950408889634f
#define LN2   0.6931471805599453f
#define CORR_L2 8.617045f   // log2(50257/128)

__device__ __forceinline__ float i2f(int x) { return __int_as_float(x); }
__device__ __forceinline__ int   f2i(float x) { return __float_as_int(x); }

// ---------------- main kernel: grid (512, 2), block 576 ----------------
// side 0: loss_cos (nei). side 1: loss_cro (voc).
__global__ __launch_bounds__(BLOCK) void cg_main(
    const int* __restrict__ sta_loc,    // (T, 8)
    const int* __restrict__ nei_loc,    // (T, 128, 8)
    const int* __restrict__ voc_loc,    // (T, 128, 8)
    const float* __restrict__ sta_emb,  // (T, 256)
    const float* __restrict__ nei_emb,  // (T, 128, 256)
    const float* __restrict__ voc_emb,  // (T, 128, 256)
    const int* __restrict__ rand_masks, // (T, 32, 8)
    float* __restrict__ wcos,           // (T, 65, 8)
    float* __restrict__ wcro)           // (T, 65, 8)
{
    const int t = blockIdx.x;
    const int side = blockIdx.y;
    const int tid = threadIdx.x;

    __shared__ int4  s_pc4[NJ * TP];    // 16 KB: {qa, qsgn, B|C, ae|A}
    __shared__ float s_cspT[TP * 132];  // transposed csp, padded
    __shared__ float s_css[NJ];
    __shared__ float s_w[NJ];           // eu (side0) or A_k (side1)
    __shared__ float s_dot[NJ], s_nn[NJ];
    __shared__ float s_Mpart[9 * 8];
    __shared__ float s_ss;
    __shared__ int   s_sta[TP];
    __shared__ int   s_rand[256];

    if (tid < TP) s_sta[tid] = sta_loc[t * TP + tid];
    if (tid < 256) s_rand[tid] = rand_masks[t * 256 + tid];

    // ---- P1: embedding partial sums (4 threads per row; waves 0-7) ----
    if (tid < 512) {
        const float* emb = side ? voc_emb : nei_emb;
        const int g = tid >> 2, sub = tid & 3;
        const float4* ep = (const float4*)(emb + ((size_t)t * NJ + g) * 256);
        const float4* sp = (const float4*)(sta_emb + (size_t)t * 256);
        float dd = 0.f, nn = 0.f, ss = 0.f;
        #pragma unroll
        for (int i = 0; i < 16; ++i) {
            const int i4 = sub + 4 * i;
            const float4 b = ep[i4];
            nn += b.x * b.x + b.y * b.y + b.z * b.z + b.w * b.w;
            if (side == 0) {
                const float4 a = sp[i4];
                dd += a.x * b.x + a.y * b.y + a.z * b.z + a.w * b.w;
            }
            if (g == 0) {
                const float4 a = sp[i4];
                ss += a.x * a.x + a.y * a.y + a.z * a.z + a.w * a.w;
            }
        }
        nn += __shfl_xor(nn, 1); nn += __shfl_xor(nn, 2);
        if (side == 0) { dd += __shfl_xor(dd, 1); dd += __shfl_xor(dd, 2); }
        if (g == 0)    { ss += __shfl_xor(ss, 1); ss += __shfl_xor(ss, 2); }
        if (sub == 0) {
            s_nn[g] = nn;
            if (side == 0) s_dot[g] = dd;
            if (g == 0) s_ss = ss;
        }
    }
    __syncthreads();

    // ---- P2: stage qa/qsgn + csp (transposed). 1024 items, stride 576 ----
    {
        const int* loc = side ? voc_loc : nei_loc;
        for (int item = tid; item < NJ * TP; item += BLOCK) {
            const int pl = loc[t * (NJ * TP) + item];
            const int qa = pl < 0 ? -pl : pl;
            const int qsgn = pl & 0x80000000;
            const int sta = s_sta[item & 7];
            const int sa = sta < 0 ? -sta : sta;
            const int x = sa ^ qa;
            const float u0 = fmaf((float)__clz(x + 1), 0.0625f, -1.0f);
            const float csp = i2f(f2i(u0) ^ ((sta ^ pl) & 0x80000000));
            ((int2*)&s_pc4[item])[0] = make_int2(qa, qsgn);
            s_cspT[(item & 7) * 132 + (item >> 3)] = csp;
        }
    }
    __syncthreads();

    // ---- P3: css reduce + eu / A ----
    if (tid < NJ) {
        float cs = 0.f;
        #pragma unroll
        for (int p = 0; p < TP; ++p) cs += s_cspT[p * 132 + tid];
        s_css[tid] = cs;
        const float ns = sqrtf(s_ss);
        const float nn = s_nn[tid];
        if (side == 0)
            s_w[tid] = s_dot[tid] / (fmaxf(sqrtf(nn), 1e-12f) * fmaxf(ns, 1e-12f));
        else
            s_w[tid] = ns * sqrtf(nn) * (0.125f * LOG2E);   // A_k (>= 0)
    }
    __syncthreads();

    // ---- P4: repack {B|C, ae|A}; side1 also per-(wave,p) max of (C + A) ----
    // note: stride 576 is a multiple of 8, so p = tid&7 is invariant per thread
    {
        float mloc = -INFINITY;
        for (int item = tid; item < NJ * TP; item += BLOCK) {
            const int j = item >> 3, p = item & 7;
            const float csp = s_cspT[p * 132 + j];
            const float b = s_css[j] - csp;
            const float w = s_w[j];
            float z2, w2;
            if (side == 0) { z2 = fmaf(b, 0.125f, -w); w2 = fabsf(w); }
            else {
                z2 = fmaf(b, w, j ? CORR_L2 : 0.0f);
                w2 = w;
                mloc = fmaxf(mloc, z2 + w);
            }
            ((int2*)&s_pc4[item])[1] = make_int2(f2i(z2), f2i(w2));
        }
        if (side) {
            mloc = fmaxf(mloc, __shfl_xor(mloc, 8));
            mloc = fmaxf(mloc, __shfl_xor(mloc, 16));
            mloc = fmaxf(mloc, __shfl_xor(mloc, 32));
            const int lane = tid & 63;
            if (lane < 8) s_Mpart[(tid >> 6) * 8 + lane] = mloc;
        }
    }
    __syncthreads();

    // ---- P5: UNIFORM path, one thread per (c, p), tid < 520 ----
    // exact-tie candidates (e.g. c=30/31/63/64 when u==0 for all pos) must be
    // bitwise identical so first-min argmin matches numpy — single code path.
    if (tid < NC * TP) {
        const int c = tid >> 3, p = tid & 7;
        const int sta = s_sta[p];
        int v;
        if (c == 32) v = sta;
        else {
            const int cc = (c < 32) ? c : (c - 33);
            const int h = cc >> 1;
            const int r = (sta ^ (1 << h)) ^ (s_rand[cc * TP + p] & ((1 << h) - 1));
            v = (c < 32) ? r : -r;
        }
        const int va = v < 0 ? -v : v;
        const int vs = v & 0x80000000;
        const int4* pc = s_pc4 + p;

        if (side == 0) {
            float lc0 = 0.f, lc1 = 0.f;
            #pragma unroll 2
            for (int j = 0; j < NJ; j += 2) {
                const int4 a = pc[j * 8];
                const int4 b = pc[(j + 1) * 8];
                {
                    const int x = va ^ a.x;
                    const float u8 = fmaf((float)__clz(x + 1), 0.0078125f, -0.125f);
                    const float d = i2f(f2i(u8) ^ (vs ^ a.y)) + i2f(a.z);
                    lc0 = fmaf(d * d, i2f(a.w), lc0);
                }
                {
                    const int x = va ^ b.x;
                    const float u8 = fmaf((float)__clz(x + 1), 0.0078125f, -0.125f);
                    const float d = i2f(f2i(u8) ^ (vs ^ b.y)) + i2f(b.z);
                    lc1 = fmaf(d * d, i2f(b.w), lc1);
                }
            }
            wcos[t * (NC * TP) + tid] = (lc0 + lc1) * 0.0078125f;
        } else {
            float M = s_Mpart[p];
            #pragma unroll
            for (int w = 1; w < 9; ++w) M = fmaxf(M, s_Mpart[w * 8 + p]);
            // peel k = 0 (need z0) and k = 1 (second accumulator)
            float z0;
            {
                const int4 a = pc[0];
                const int x = va ^ a.x;
                const float u0 = fmaf((float)__clz(x + 1), 0.0625f, -1.0f);
                const float u = i2f(f2i(u0) ^ (vs ^ a.y));
                z0 = fmaf(u, i2f(a.w), i2f(a.z)) - M;
            }
            float s0 = __builtin_amdgcn_exp2f(z0), s1;
            {
                const int4 a = pc[8];
                const int x = va ^ a.x;
                const float u0 = fmaf((float)__clz(x + 1), 0.0625f, -1.0f);
                const float u = i2f(f2i(u0) ^ (vs ^ a.y));
                s1 = __builtin_amdgcn_exp2f(fmaf(u, i2f(a.w), i2f(a.z)) - M);
            }
            #pragma unroll 2
            for (int k = 2; k < NJ; k += 2) {
                const int4 a = pc[k * 8];
                const int4 b = pc[(k + 1) * 8];
                {
                    const int x = va ^ a.x;
                    const float u0 = fmaf((float)__clz(x + 1), 0.0625f, -1.0f);
                    const float u = i2f(f2i(u0) ^ (vs ^ a.y));
                    s0 += __builtin_amdgcn_exp2f(fmaf(u, i2f(a.w), i2f(a.z)) - M);
                }
                {
                    const int x = va ^ b.x;
                    const float u0 = fmaf((float)__clz(x + 1), 0.0625f, -1.0f);
                    const float u = i2f(f2i(u0) ^ (vs ^ b.y));
                    s1 += __builtin_amdgcn_exp2f(fmaf(u, i2f(b.w), i2f(b.z)) - M);
                }
            }
            const float S = fmaxf(s0 + s1, 1e-38f);
            wcro[t * (NC * TP) + tid] = (__builtin_amdgcn_logf(S) - z0) * LN2;
        }
    }
}

// ---------------- finalize: argmin + gather + means. grid 512 x 128 ----------------
__global__ __launch_bounds__(128) void cg_fin(
    const int* __restrict__ sta_loc, const int* __restrict__ rand_masks,
    const float* __restrict__ wcos, const float* __restrict__ wcro,
    float* __restrict__ out)
{
    const int t = blockIdx.x, tid = threadIdx.x;
    __shared__ float sc[NC * TP], sr[NC * TP];
    for (int i = tid; i < NC * TP; i += 128) {
        sc[i] = wcos[t * (NC * TP) + i];
        sr[i] = wcro[t * (NC * TP) + i];
    }
    __syncthreads();
    float vc = 0.f, vr = 0.f, vt = 0.f;
    if (tid < TP) {
        float best = INFINITY, blc = 0.f, blr = 0.f;
        int bc = 0;
        for (int c = 0; c < NC; ++c) {
            const float lc = sc[c * TP + tid];
            const float lr = sr[c * TP + tid];
            const float lt = fmaf(0.1f, lr, lc);
            if (lt < best) { best = lt; bc = c; blc = lc; blr = lr; }
        }
        const int sta = sta_loc[t * TP + tid];
        int v;
        if (bc == 32) v = sta;
        else {
            const int cc = (bc < 32) ? bc : (bc - 33);
            const int h = cc >> 1;
            const int r = (sta ^ (1 << h)) ^ (rand_masks[t * 256 + cc * TP + tid] & ((1 << h) - 1));
            v = (bc < 32) ? r : -r;
        }
        out[t * TP + tid] = (float)v;
        vc = blc; vr = blr; vt = best;
    }
    vc += __shfl_xor(vc, 1); vc += __shfl_xor(vc, 2); vc += __shfl_xor(vc, 4);
    vr += __shfl_xor(vr, 1); vr += __shfl_xor(vr, 2); vr += __shfl_xor(vr, 4);
    vt += __shfl_xor(vt, 1); vt += __shfl_xor(vt, 2); vt += __shfl_xor(vt, 4);
    if (tid == 0) {
        out[T_DIM * TP + t] = vc * 0.125f;
        out[T_DIM * TP + T_DIM + t] = vr * 0.125f;
        out[T_DIM * TP + 2 * T_DIM + t] = vt * 0.125f;
    }
}

extern "C" void kernel_launch(void* const* d_in, const int* in_sizes, int n_in,
                              void* d_out, int out_size, void* d_ws, size_t ws_size,
                              hipStream_t stream) {
    const int* sta_loc = (const int*)d_in[0];
    const int* nei_loc = (const int*)d_in[1];
    const int* voc_loc = (const int*)d_in[2];
    const float* sta_emb = (const float*)d_in[3];
    const float* nei_emb = (const float*)d_in[4];
    const float* voc_emb = (const float*)d_in[5];
    const int* rand_masks = (const int*)d_in[6];
    float* out = (float*)d_out;

    float* wcos = (float*)d_ws;
    float* wcro = wcos + (size_t)T_DIM * NC * TP;

    cg_main<<<dim3(T_DIM, 2), BLOCK, 0, stream>>>(
        sta_loc, nei_loc, voc_loc, sta_emb, nei_emb, voc_emb, rand_masks, wcos, wcro);
    cg_fin<<<T_DIM, 128, 0, stream>>>(sta_loc, rand_masks, wcos, wcro, out);
}